// Round 8
// baseline (968.399 us; speedup 1.0000x reference)
//
#include <hip/hip_runtime.h>
#include <math.h>
#include <stdint.h>

// Problem constants
#define BB   32     // batch
#define HB   16     // batch per block (b-split: 2 blocks per n-group)
#define NN   2048   // input capsules
#define KK   16     // input dim
#define CC   32     // output capsules
#define DD   32     // capsule dim
#define NCOL 1024   // CC*DD
#define NPB  8      // n per block
#define WT   (KK * NCOL)          // 16384 floats = one 64 KB W tile
#define OSZ  (BB * NCOL)          // 32768 floats = one full o/partial image
#define NGRP (NN / NPB)           // 256 partial images
#define NSLICE 8                  // reduce tree fan-in stage 1: 256 -> 8
#define KP   17                   // padded k-stride for ush (conflict-free)

// Ladder (R0..R7):
//  - 1024-thr blocks: hard 64-VGPR pin (4x confirmed). LDS-staged W with
//    per-iter barriers serializes (R0 95us / R3 148us). Direct-W at 64 VGPR
//    spills GBs (R4/R5).
//  - R7: wave-autonomous routing (one wave owns b-quad x all 32 caps;
//    logits via octet shuffles, softmax via cross-octet shuffles; ZERO
//    main-loop barriers) -> 115us. Post-mortem: 128 acc floats/wave forced
//    opart spill (~12 MB) and left 0 regs for load pipelining; grid 256 =
//    1 block/CU = 2 waves/SIMD -> latency exposed (VALUBusy 20%, occ 20%).
// R8 (this): same autonomous structure, HALF the per-wave state, DOUBLE the
// occupancy. 8 waves x 2 b's = 16 b per block; grid = 2 b-halves x 256
// n-groups = 512 blocks = 2 blocks/CU = 4 waves/SIMD. accU[2][4][4]+opart
// = 64 acc floats -> ~100 VGPR, no spill, ~25 regs for W-load pipelining.
// XCD pairing: b-halves g, g+256 share W tiles via same-XCD L2 (256%8==0).
// ush k-stride padded to 17 -> staging writes conflict-free (was 16-way,
// 491K conflict cycles in R7).
__global__ __launch_bounds__(512) __attribute__((amdgpu_waves_per_eu(2)))
void caps_stage(const float* __restrict__ u, const float* __restrict__ W,
                const float* __restrict__ onorm, float* __restrict__ part)
{
    __shared__ float ush[NPB * KK * KP];   // 8.5 KB: [n][k][b(16)+pad]

    const int tid  = threadIdx.x;
    const int wv   = tid >> 6;         // wave 0..7
    const int lane = tid & 63;
    const int oct  = lane >> 3;        // octet 0..7 (capsule group)
    const int dq   = lane & 7;         // d-quad within capsule
    const int b0   = wv << 1;          // this wave's 2 local batches

    const int ngrp  = blockIdx.x & 255;
    const int bhalf = blockIdx.x >> 8;
    const int n0    = ngrp * NPB;
    const int bbase = bhalf * HB;      // global b offset

    // stage u (coalesced global read; padded LDS write -> conflict-free)
    for (int idx = tid; idx < NPB * KK * HB; idx += 512) {
        const int k = idx & 15, b = (idx >> 4) & 15, n = idx >> 8;
        ush[n * (KK * KP) + k * KP + b] =
            u[(size_t)(bbase + b) * (NN * KK) + (size_t)(n0 + n) * KK + k];
    }
    __syncthreads();   // the ONLY barrier in the kernel

    // per-lane W base: cols 4*lane (+256*j for quad-group j)
    const float* wp = W + (size_t)n0 * WT + (lane << 2);

    float opart[2][4][4];              // [b][j][e]
#pragma unroll
    for (int b = 0; b < 2; ++b)
#pragma unroll
        for (int j = 0; j < 4; ++j)
#pragma unroll
            for (int e = 0; e < 4; ++e) opart[b][j][e] = 0.f;

    for (int nn = 0; nn < NPB; ++nn) {
        const float* un = &ush[nn * (KK * KP)];

        float accU[2][4][4];
#pragma unroll
        for (int b = 0; b < 2; ++b)
#pragma unroll
            for (int j = 0; j < 4; ++j)
#pragma unroll
                for (int e = 0; e < 4; ++e) accU[b][j][e] = 0.f;

#pragma unroll
        for (int k = 0; k < KK; ++k) {
            // 4 coalesced float4 W loads (64 indep loads per n per wave)
            const float4 w0 = *(const float4*)(wp + k * NCOL);
            const float4 w1 = *(const float4*)(wp + k * NCOL + 256);
            const float4 w2 = *(const float4*)(wp + k * NCOL + 512);
            const float4 w3 = *(const float4*)(wp + k * NCOL + 768);
            // LDS broadcast reads (wave-uniform addr)
            const float u0 = un[k * KP + b0];
            const float u1 = un[k * KP + b0 + 1];
            const float us[2] = {u0, u1};
#pragma unroll
            for (int b = 0; b < 2; ++b) {
                accU[b][0][0] = fmaf(us[b], w0.x, accU[b][0][0]);
                accU[b][0][1] = fmaf(us[b], w0.y, accU[b][0][1]);
                accU[b][0][2] = fmaf(us[b], w0.z, accU[b][0][2]);
                accU[b][0][3] = fmaf(us[b], w0.w, accU[b][0][3]);
                accU[b][1][0] = fmaf(us[b], w1.x, accU[b][1][0]);
                accU[b][1][1] = fmaf(us[b], w1.y, accU[b][1][1]);
                accU[b][1][2] = fmaf(us[b], w1.z, accU[b][1][2]);
                accU[b][1][3] = fmaf(us[b], w1.w, accU[b][1][3]);
                accU[b][2][0] = fmaf(us[b], w2.x, accU[b][2][0]);
                accU[b][2][1] = fmaf(us[b], w2.y, accU[b][2][1]);
                accU[b][2][2] = fmaf(us[b], w2.z, accU[b][2][2]);
                accU[b][2][3] = fmaf(us[b], w2.w, accU[b][2][3]);
                accU[b][3][0] = fmaf(us[b], w3.x, accU[b][3][0]);
                accU[b][3][1] = fmaf(us[b], w3.y, accU[b][3][1]);
                accU[b][3][2] = fmaf(us[b], w3.z, accU[b][3][2]);
                accU[b][3][3] = fmaf(us[b], w3.w, accU[b][3][3]);
            }
        }
        wp += WT;   // next n's tile

        // ---- wave-local logits + softmax (no LDS, no barriers) ----
        float cv[2][4];
#pragma unroll
        for (int b = 0; b < 2; ++b) {
            const int gb = bbase + b0 + b;
            float L[4];
#pragma unroll
            for (int j = 0; j < 4; ++j) {
                // cap = oct + 8j; onorm dot over this lane's 4 d's
                const float4 on4 = *(const float4*)(
                    onorm + ((size_t)gb * CC + oct + (j << 3)) * DD + (dq << 2));
                float p = accU[b][j][0] * on4.x + accU[b][j][1] * on4.y
                        + accU[b][j][2] * on4.z + accU[b][j][3] * on4.w;
                p += __shfl_xor(p, 1);     // octet-internal: sum 8 d-quads
                p += __shfl_xor(p, 2);
                p += __shfl_xor(p, 4);
                L[j] = p;
            }
            // softmax over 32 caps: per-lane max over j, then across octets
            float mx = fmaxf(fmaxf(L[0], L[1]), fmaxf(L[2], L[3]));
            mx = fmaxf(mx, __shfl_xor(mx, 8));
            mx = fmaxf(mx, __shfl_xor(mx, 16));
            mx = fmaxf(mx, __shfl_xor(mx, 32));
            float s = 0.f;
#pragma unroll
            for (int j = 0; j < 4; ++j) { L[j] = __expf(L[j] - mx); s += L[j]; }
            s += __shfl_xor(s, 8);
            s += __shfl_xor(s, 16);
            s += __shfl_xor(s, 32);
            const float inv = 1.f / s;
#pragma unroll
            for (int j = 0; j < 4; ++j) cv[b][j] = L[j] * inv;
        }

        // ---- opart += c * U ----
#pragma unroll
        for (int b = 0; b < 2; ++b)
#pragma unroll
            for (int j = 0; j < 4; ++j)
#pragma unroll
                for (int e = 0; e < 4; ++e)
                    opart[b][j][e] = fmaf(cv[b][j], accU[b][j][e], opart[b][j][e]);
    }

    // flush partials: float4 at col 256*j + 4*lane -> coalesced
    float* my = part + (size_t)ngrp * OSZ
              + (size_t)(bbase + b0) * NCOL + (lane << 2);
#pragma unroll
    for (int b = 0; b < 2; ++b)
#pragma unroll
        for (int j = 0; j < 4; ++j) {
            float4 v;
            v.x = opart[b][j][0]; v.y = opart[b][j][1];
            v.z = opart[b][j][2]; v.w = opart[b][j][3];
            *(float4*)&my[b * NCOL + (j << 8)] = v;
        }
}

// Level-1 reduce: 256 partial images -> NSLICE slice images (32 each).
__global__ __launch_bounds__(256) void caps_reduce1(
    const float* __restrict__ part, float* __restrict__ ws2)
{
    const int gid   = blockIdx.x * 256 + threadIdx.x;     // 0..65535
    const int slice = gid >> 13;                          // 0..7
    const int q     = gid & 8191;                         // col-quad
    float4 acc = make_float4(0.f, 0.f, 0.f, 0.f);
    const float* p = part + ((size_t)slice * 32) * OSZ + (q << 2);
#pragma unroll 8
    for (int j = 0; j < 32; ++j) {
        const float4 v = *(const float4*)(p + (size_t)j * OSZ);
        acc.x += v.x; acc.y += v.y; acc.z += v.z; acc.w += v.w;
    }
    *(float4*)(ws2 + ((size_t)gid << 2)) = acc;
}

// Level-2 reduce + row op. mode 0: l2-normalize. mode 1: squash.
__global__ __launch_bounds__(256) void caps_reduce2(
    const float* __restrict__ ws2, float* __restrict__ dst, int mode)
{
    const int q = blockIdx.x * 256 + threadIdx.x;         // 0..8191
    float4 acc = make_float4(0.f, 0.f, 0.f, 0.f);
#pragma unroll
    for (int s = 0; s < NSLICE; ++s) {
        const float4 v = *(const float4*)(ws2 + ((size_t)s << 15) + (q << 2));
        acc.x += v.x; acc.y += v.y; acc.z += v.z; acc.w += v.w;
    }
    float s2 = acc.x * acc.x + acc.y * acc.y + acc.z * acc.z + acc.w * acc.w;
    s2 += __shfl_xor(s2, 1);
    s2 += __shfl_xor(s2, 2);
    s2 += __shfl_xor(s2, 4);
    float scale;
    if (mode == 0) {
        scale = rsqrtf(fmaxf(s2, 1e-12f));
    } else {
        scale = (s2 / (1.f + s2)) / sqrtf(s2 + 1e-7f);
    }
    float4 o;
    o.x = acc.x * scale; o.y = acc.y * scale;
    o.z = acc.z * scale; o.w = acc.w * scale;
    *(float4*)(dst + ((size_t)q << 2)) = o;
}

extern "C" void kernel_launch(void* const* d_in, const int* in_sizes, int n_in,
                              void* d_out, int out_size, void* d_ws, size_t ws_size,
                              hipStream_t stream)
{
    const float* u = (const float*)d_in[0];   // (32, 2048, 16)
    const float* W = (const float*)d_in[1];   // (2048, 16, 1024)
    float* out = (float*)d_out;               // (32, 32, 32)

    // ws layout: part (256*32768 fl = 32 MB) | ws2 (1 MB) | onorm (128 KB)
    float* part  = (float*)d_ws;
    float* ws2   = part + (size_t)NGRP * OSZ;
    float* onorm = ws2 + (size_t)NSLICE * OSZ;

    // onorm = 0 => logits 0 => softmax uniform 1/32 (exactly iteration 0)
    hipMemsetAsync(onorm, 0, (size_t)OSZ * sizeof(float), stream);

    for (int it = 0; it < 3; ++it) {
        caps_stage<<<2 * NGRP, 512, 0, stream>>>(u, W, onorm, part);
        caps_reduce1<<<256, 256, 0, stream>>>(part, ws2);
        if (it < 2)
            caps_reduce2<<<32, 256, 0, stream>>>(ws2, onorm, 0);  // l2-normalize
        else
            caps_reduce2<<<32, 256, 0, stream>>>(ws2, out, 1);    // squash -> d_out
    }
}